// Round 19
// baseline (66.367 us; speedup 1.0000x reference)
//
#include <hip/hip_runtime.h>
#include <hip/hip_bf16.h>

#define N_PTS 4096
#define M_PTS 16384
#define CIN   256
#define CSK   128
#define KDIM  384   // CIN + CSK
#define HDIM  256
#define NSHARD 32
#define SHPTS (N_PTS / NSHARD)   // 128

typedef unsigned int  u32;
typedef unsigned short u16;
typedef __attribute__((ext_vector_type(8))) short bf16x8;
typedef __attribute__((ext_vector_type(4))) float f32x4;

__device__ __forceinline__ u16 f2bf(float f) {
    union { float f; u32 i; } w; w.f = f;
    u32 x = w.i;
    u32 r = x + 0x7fffu + ((x >> 16) & 1u);   // RTNE
    return (u16)(r >> 16);
}

// strict "better" with lower-index tie-break (stable-sort semantics)
__device__ __forceinline__ bool ltk(float s, int p, float t, int i) {
    return (s < t) || (s == t && p < i);
}
__device__ __forceinline__ void ins3(float s, int p,
                                     float& t0, float& t1, float& t2,
                                     int& i0, int& i1, int& i2) {
    if (ltk(s, p, t2, i2)) {
        if (ltk(s, p, t1, i1)) {
            t2 = t1; i2 = i1;
            if (ltk(s, p, t0, i0)) { t1 = t0; i1 = i0; t0 = s; i0 = p; }
            else                   { t1 = s;  i1 = p; }
        } else { t2 = s; i2 = p; }
    }
}

// branchless sorted top-3 insert, strict < (ascending-index stream => stable)
#define INS3BL(s, p, t0, t1, t2, i0, i1, i2)                              \
    {                                                                     \
        float _o0 = t0, _o1 = t1, _o2 = t2;                               \
        int _a0 = i0, _a1 = i1, _a2 = i2;                                 \
        bool _c0 = (s) < _o0, _c1 = (s) < _o1, _c2 = (s) < _o2;           \
        t0 = _c0 ? (s) : _o0;              i0 = _c0 ? (p) : _a0;          \
        t1 = _c0 ? _o0 : (_c1 ? (s) : _o1); i1 = _c0 ? _a0 : (_c1 ? (p) : _a1); \
        t2 = _c1 ? _o1 : (_c2 ? (s) : _o2); i2 = _c1 ? _a1 : (_c2 ? (p) : _a2); \
    }

// branchless top-3 insert: values via min/med3, indices via cmp+sel.
// Proven bit-exact (rounds 9/14/15). Strict <, stable for ascending streams.
#define INS3MM(s, p, t0, t1, t2, i0, i1, i2)                              \
    {                                                                     \
        bool _c0 = (s) < t0, _c1 = (s) < t1, _c2 = (s) < t2;              \
        int _oi0 = i0, _oi1 = i1;                                         \
        i0 = _c0 ? (p) : i0;                                              \
        i1 = _c0 ? _oi0 : (_c1 ? (p) : i1);                               \
        i2 = _c1 ? _oi1 : (_c2 ? (p) : i2);                               \
        float _ot0 = t0, _ot1 = t1;                                       \
        t0 = fminf(t0, (s));                                              \
        t1 = __builtin_amdgcn_fmed3f(_ot0, t1, (s));                      \
        t2 = __builtin_amdgcn_fmed3f(_ot1, t2, (s));                      \
    }

// ---------------------------------------------------------------------------
// Kernel 1 (FAT):
//   blocks 0..255   : min-only sharded scan, EIGHT queries/thread (one LDS
//                     broadcast feeds 48 VALU ops; halves LDS traffic vs 4q)
//   blocks 256..383 : gemm_Z                                    [R16 proven]
//   blocks 384..639 : W-transpose prep: W1bT [256][128], W2T [256][256] bf16
// ---------------------------------------------------------------------------
__global__ __launch_bounds__(256) void scanM_gemmZ_prep(
    const float* __restrict__ pos,
    const float* __restrict__ pos_skip,
    float* __restrict__ candM,
    const float* __restrict__ x,
    const float* __restrict__ W1,
    const float* __restrict__ W2,
    float* __restrict__ Z,
    u16* __restrict__ W1bT,
    u16* __restrict__ W2T)
{
    const int bid = blockIdx.x;
    const int tid = threadIdx.x;

    if (bid < 256) {
        // ------------------- scanM: 8 queries per thread -------------------
        __shared__ float4 spts[SHPTS];     // 2 KB
        const int bx = bid & 7, sh = bid >> 3;
        const int pbase = sh * SHPTS;

        if (tid < SHPTS) {
            const int i = pbase + tid;
            float px = pos[3 * i], py = pos[3 * i + 1], pz = pos[3 * i + 2];
            float pn = __fadd_rn(__fadd_rn(__fmul_rn(px, px), __fmul_rn(py, py)),
                                 __fmul_rn(pz, pz));
            spts[tid] = make_float4(px, py, pz, pn);
        }

        const int mb = bx * 2048 + tid;    // queries mb + q*256, q=0..7
        float qx[8], qy[8], qz[8], qn[8];
        #pragma unroll
        for (int q = 0; q < 8; ++q) {
            const int m = mb + q * 256;
            qx[q] = pos_skip[3 * m];
            qy[q] = pos_skip[3 * m + 1];
            qz[q] = pos_skip[3 * m + 2];
            qn[q] = __fadd_rn(__fadd_rn(__fmul_rn(qx[q], qx[q]), __fmul_rn(qy[q], qy[q])),
                              __fmul_rn(qz[q], qz[q]));
        }
        __syncthreads();

        float e[8] = {3.4e38f, 3.4e38f, 3.4e38f, 3.4e38f,
                      3.4e38f, 3.4e38f, 3.4e38f, 3.4e38f};

        #pragma unroll 4
        for (int j = 0; j < SHPTS; ++j) {
            float4 v = spts[j];            // wave-uniform broadcast read
            #pragma unroll
            for (int q = 0; q < 8; ++q) {
                float b = __fmaf_rn(qz[q], v.z, __fmaf_rn(qy[q], v.y, __fmul_rn(qx[q], v.x)));
                float s = __fadd_rn(__fmaf_rn(-2.0f, b, qn[q]), v.w);
                e[q] = fminf(e[q], s);
            }
        }

        #pragma unroll
        for (int q = 0; q < 8; ++q)
            candM[(size_t)sh * M_PTS + mb + q * 256] = e[q];
    } else if (bid < 384) {
        // ------------------- gemm_Z: Z = bf16(x) @ bf16(W1a) ---------------
        __shared__ alignas(16) u16 Bs[64][40];
        const int id = bid - 256;
        const int w = tid >> 6, l = tid & 63;
        const int bm = (id & 31) * 128;
        const int bn = (id >> 5) * 64;
        const int lr = l & 15, lg = l >> 4;

        f32x4 acc[2][4];
        #pragma unroll
        for (int mt = 0; mt < 2; ++mt)
            #pragma unroll
            for (int nt = 0; nt < 4; ++nt)
                acc[mt][nt] = (f32x4){0.f, 0.f, 0.f, 0.f};

        const int sc = tid >> 2;
        const int sk = (tid & 3) * 8;

        for (int k0 = 0; k0 < CIN; k0 += 32) {
            #pragma unroll
            for (int j = 0; j < 8; ++j)
                Bs[sc][sk + j] = f2bf(W1[(size_t)(k0 + sk + j) * HDIM + bn + sc]);
            __syncthreads();

            bf16x8 af[2];
            #pragma unroll
            for (int mt = 0; mt < 2; ++mt) {
                const float* xp = x + (size_t)(bm + w * 32 + mt * 16 + lr) * CIN + k0 + lg * 8;
                float4 h0 = *reinterpret_cast<const float4*>(xp);
                float4 h1 = *reinterpret_cast<const float4*>(xp + 4);
                af[mt][0] = (short)f2bf(h0.x); af[mt][1] = (short)f2bf(h0.y);
                af[mt][2] = (short)f2bf(h0.z); af[mt][3] = (short)f2bf(h0.w);
                af[mt][4] = (short)f2bf(h1.x); af[mt][5] = (short)f2bf(h1.y);
                af[mt][6] = (short)f2bf(h1.z); af[mt][7] = (short)f2bf(h1.w);
            }
            #pragma unroll
            for (int nt = 0; nt < 4; ++nt) {
                bf16x8 bf = *reinterpret_cast<const bf16x8*>(&Bs[nt * 16 + lr][lg * 8]);
                #pragma unroll
                for (int mt = 0; mt < 2; ++mt)
                    acc[mt][nt] = __builtin_amdgcn_mfma_f32_16x16x32_bf16(
                        af[mt], bf, acc[mt][nt], 0, 0, 0);
            }
            __syncthreads();
        }

        #pragma unroll
        for (int nt = 0; nt < 4; ++nt) {
            const int col = bn + nt * 16 + lr;
            #pragma unroll
            for (int mt = 0; mt < 2; ++mt)
                #pragma unroll
                for (int i = 0; i < 4; ++i) {
                    const int row = bm + w * 32 + mt * 16 + lg * 4 + i;
                    Z[(size_t)row * HDIM + col] = acc[mt][nt][i];
                }
        }
    } else {
        // ------------------- W-transpose prep (one output col per block) ---
        const int n = bid - 384;               // 0..255
        W2T[(size_t)n * HDIM + tid] = f2bf(W2[(size_t)tid * HDIM + n]);
        if (tid >= 128) {
            const int k = tid - 128;
            W1bT[(size_t)n * CSK + k] = f2bf(W1[(size_t)(CIN + k) * HDIM + n]);
        }
    }
}

// ---------------------------------------------------------------------------
// Kernel 2 (MFMA, + fused KNN finish): grid (256, 2) = 64 rows x 128 cols.
//   Prologue (R16-proven select_rescan, verbatim, results in LDS):
//     Phase A: 4 slots/query pick 3 smallest (shard-min, sh) keys;
//     Phase B: slots rescan the 3 shards (INS3MM); slot 0 merges -> w,idx.
//   GEMM: H = relu(bf16(x_skip)@W1bT + sum_k w_k Z[i_k] + b1) -> Hbuf (bf16).
//   Selection duplicated across the 2 column blocks (cheap); nbrw/nbri never
//   touch global. K-accumulation order unchanged -> H bit-identical to R18.
// ---------------------------------------------------------------------------
__global__ __launch_bounds__(256) void gemm_SHsel(
    const float* __restrict__ pos,
    const float* __restrict__ pos_skip,
    const float* __restrict__ candM,
    const float* __restrict__ x_skip, const u16* __restrict__ W1bT,
    const float* __restrict__ b1, const float* __restrict__ Z,
    u16* __restrict__ H)
{
    __shared__ float sv[64][4][3];
    __shared__ int   si[64][4][3];
    __shared__ u32   ssel[64];
    __shared__ float4 nw[64];
    __shared__ uint4  ni[64];
    __shared__ alignas(16) u16 Bs[128][40];    // 10.2 KB

    const int tid  = threadIdx.x;
    const int ql   = tid >> 2;
    const int slot = tid & 3;
    const int bm   = blockIdx.x * 64;
    const int bn   = blockIdx.y * 128;
    const int m    = bm + ql;

    // ======================= Prologue: selection ============================
    {
        float t0 = 3.4e38f, t1 = 3.4e38f, t2 = 3.4e38f;
        int   s0 = 63, s1 = 63, s2 = 63;
        #pragma unroll
        for (int k = 0; k < 8; ++k) {
            const int sh = slot * 8 + k;
            float mn = candM[(size_t)sh * M_PTS + m];
            INS3BL(mn, sh, t0, t1, t2, s0, s1, s2);
        }
        sv[ql][slot][0] = t0; sv[ql][slot][1] = t1; sv[ql][slot][2] = t2;
        si[ql][slot][0] = s0; si[ql][slot][1] = s1; si[ql][slot][2] = s2;
    }
    __syncthreads();
    if (slot == 0) {
        float t0 = 3.4e38f, t1 = 3.4e38f, t2 = 3.4e38f;
        int   s0 = 63, s1 = 63, s2 = 63;
        #pragma unroll
        for (int s = 0; s < 4; ++s)
            #pragma unroll
            for (int k = 0; k < 3; ++k)
                ins3(sv[ql][s][k], si[ql][s][k], t0, t1, t2, s0, s1, s2);
        ssel[ql] = (u32)s0 | ((u32)s1 << 8) | ((u32)s2 << 16);
    }
    __syncthreads();
    const u32 sel = ssel[ql];

    if (slot < 3) {
        const int sh = (sel >> (8 * slot)) & 63;
        const int pb = sh * SHPTS;

        const float qx = pos_skip[3 * m];
        const float qy = pos_skip[3 * m + 1];
        const float qz = pos_skip[3 * m + 2];
        const float qn = __fadd_rn(__fadd_rn(__fmul_rn(qx, qx), __fmul_rn(qy, qy)),
                                   __fmul_rn(qz, qz));

        float t0 = 3.4e38f, t1 = 3.4e38f, t2 = 3.4e38f;
        int   i0 = 0x7fffffff, i1 = 0x7fffffff, i2 = 0x7fffffff;

        #pragma unroll 4
        for (int j = 0; j < SHPTS; ++j) {
            const int p = pb + j;
            float px = pos[3 * p], py = pos[3 * p + 1], pz = pos[3 * p + 2];
            float pn = __fadd_rn(__fadd_rn(__fmul_rn(px, px), __fmul_rn(py, py)),
                                 __fmul_rn(pz, pz));
            float b = __fmaf_rn(qz, pz, __fmaf_rn(qy, py, __fmul_rn(qx, px)));
            float s = __fadd_rn(__fmaf_rn(-2.0f, b, qn), pn);
            INS3MM(s, p, t0, t1, t2, i0, i1, i2);
        }
        sv[ql][slot][0] = t0; sv[ql][slot][1] = t1; sv[ql][slot][2] = t2;
        si[ql][slot][0] = i0; si[ql][slot][1] = i1; si[ql][slot][2] = i2;
    }
    __syncthreads();

    if (slot == 0) {
        float t0 = 3.4e38f, t1 = 3.4e38f, t2 = 3.4e38f;
        int   i0 = 0x7fffffff, i1 = 0x7fffffff, i2 = 0x7fffffff;
        #pragma unroll
        for (int s = 0; s < 3; ++s)
            #pragma unroll
            for (int k = 0; k < 3; ++k)
                ins3(sv[ql][s][k], si[ql][s][k], t0, t1, t2, i0, i1, i2);

        float w0 = __fdiv_rn(1.0f, fmaxf(t0, 1e-16f));
        float w1 = __fdiv_rn(1.0f, fmaxf(t1, 1e-16f));
        float w2 = __fdiv_rn(1.0f, fmaxf(t2, 1e-16f));
        float inv = __fdiv_rn(1.0f, __fadd_rn(__fadd_rn(w0, w1), w2));
        nw[ql] = make_float4(w0 * inv, w1 * inv, w2 * inv, 0.f);
        ni[ql] = make_uint4((u32)i0, (u32)i1, (u32)i2, 0u);
    }
    __syncthreads();

    // ======================= GEMM: S + interpolate ==========================
    const int w = tid >> 6, l = tid & 63;
    const int lr = l & 15, lg = l >> 4;

    f32x4 acc[8];
    #pragma unroll
    for (int nt = 0; nt < 8; ++nt) acc[nt] = (f32x4){0.f, 0.f, 0.f, 0.f};

    const int sc = tid >> 1;          // staging col 0..127
    const int sk = (tid & 1) * 16;    // k 0 or 16

    for (int k0 = 0; k0 < CSK; k0 += 32) {
        *reinterpret_cast<bf16x8*>(&Bs[sc][sk]) =
            *reinterpret_cast<const bf16x8*>(&W1bT[(size_t)(bn + sc) * CSK + k0 + sk]);
        *reinterpret_cast<bf16x8*>(&Bs[sc][sk + 8]) =
            *reinterpret_cast<const bf16x8*>(&W1bT[(size_t)(bn + sc) * CSK + k0 + sk + 8]);
        __syncthreads();

        const float* xp = x_skip + (size_t)(bm + w * 16 + lr) * CSK + k0 + lg * 8;
        float4 h0 = *reinterpret_cast<const float4*>(xp);
        float4 h1 = *reinterpret_cast<const float4*>(xp + 4);
        bf16x8 af;
        af[0] = (short)f2bf(h0.x); af[1] = (short)f2bf(h0.y);
        af[2] = (short)f2bf(h0.z); af[3] = (short)f2bf(h0.w);
        af[4] = (short)f2bf(h1.x); af[5] = (short)f2bf(h1.y);
        af[6] = (short)f2bf(h1.z); af[7] = (short)f2bf(h1.w);

        #pragma unroll
        for (int nt = 0; nt < 8; ++nt) {
            bf16x8 bf = *reinterpret_cast<const bf16x8*>(&Bs[nt * 16 + lr][lg * 8]);
            acc[nt] = __builtin_amdgcn_mfma_f32_16x16x32_bf16(af, bf, acc[nt], 0, 0, 0);
        }
        __syncthreads();
    }

    // epilogue: blend interpolated Z rows + bias + relu -> H (bf16)
    #pragma unroll
    for (int i = 0; i < 4; ++i) {
        const int lrow = w * 16 + lg * 4 + i;
        const int row  = bm + lrow;
        const float4 wv = nw[lrow];
        const uint4  iv = ni[lrow];
        const float* z0 = Z + (size_t)(iv.x & 4095u) * HDIM;  // clamp: no OOB
        const float* z1 = Z + (size_t)(iv.y & 4095u) * HDIM;
        const float* z2 = Z + (size_t)(iv.z & 4095u) * HDIM;
        #pragma unroll
        for (int nt = 0; nt < 8; ++nt) {
            const int col = bn + nt * 16 + lr;
            float zb = wv.x * z0[col] + wv.y * z1[col] + wv.z * z2[col];
            float v = acc[nt][i] + zb + b1[col];
            H[(size_t)row * HDIM + col] = f2bf(v > 0.f ? v : 0.f);
        }
    }
}

// ---------------------------------------------------------------------------
// Kernel 3 (MFMA): out = H @ W2 + b2.  H bf16, vector B-staging from W2T.
// (R18 proven, unchanged.)
// ---------------------------------------------------------------------------
__global__ __launch_bounds__(256) void gemm2_mfma(
    const u16* __restrict__ H, const u16* __restrict__ W2T,
    const float* __restrict__ b2, float* __restrict__ out)
{
    __shared__ alignas(16) u16 Bs[64][40];
    const int tid = threadIdx.x;
    const int w = tid >> 6, l = tid & 63;
    const int bm = blockIdx.x * 128;
    const int bn = blockIdx.y * 64;
    const int lr = l & 15, lg = l >> 4;

    f32x4 acc[2][4];
    #pragma unroll
    for (int mt = 0; mt < 2; ++mt)
        #pragma unroll
        for (int nt = 0; nt < 4; ++nt)
            acc[mt][nt] = (f32x4){0.f, 0.f, 0.f, 0.f};

    const int sc = tid >> 2;
    const int sk = (tid & 3) * 8;

    for (int k0 = 0; k0 < HDIM; k0 += 32) {
        *reinterpret_cast<bf16x8*>(&Bs[sc][sk]) =
            *reinterpret_cast<const bf16x8*>(&W2T[(size_t)(bn + sc) * HDIM + k0 + sk]);
        __syncthreads();

        bf16x8 af[2];
        #pragma unroll
        for (int mt = 0; mt < 2; ++mt) {
            const int row = bm + w * 32 + mt * 16 + lr;
            af[mt] = *reinterpret_cast<const bf16x8*>(H + (size_t)row * HDIM + k0 + lg * 8);
        }
        #pragma unroll
        for (int nt = 0; nt < 4; ++nt) {
            bf16x8 bf = *reinterpret_cast<const bf16x8*>(&Bs[nt * 16 + lr][lg * 8]);
            #pragma unroll
            for (int mt = 0; mt < 2; ++mt)
                acc[mt][nt] = __builtin_amdgcn_mfma_f32_16x16x32_bf16(
                    af[mt], bf, acc[mt][nt], 0, 0, 0);
        }
        __syncthreads();
    }

    #pragma unroll
    for (int nt = 0; nt < 4; ++nt) {
        const int col = bn + nt * 16 + lr;
        const float bias = b2[col];
        #pragma unroll
        for (int mt = 0; mt < 2; ++mt)
            #pragma unroll
            for (int i = 0; i < 4; ++i) {
                const int row = bm + w * 32 + mt * 16 + lg * 4 + i;
                out[(size_t)row * HDIM + col] = acc[mt][nt][i] + bias;
            }
    }
}

// ---------------------------------------------------------------------------
extern "C" void kernel_launch(void* const* d_in, const int* in_sizes, int n_in,
                              void* d_out, int out_size, void* d_ws, size_t ws_size,
                              hipStream_t stream) {
    const float* x        = (const float*)d_in[0];
    const float* pos      = (const float*)d_in[1];
    const float* x_skip   = (const float*)d_in[2];
    const float* pos_skip = (const float*)d_in[3];
    const float* W1       = (const float*)d_in[4];
    const float* b1       = (const float*)d_in[5];
    const float* W2       = (const float*)d_in[6];
    const float* b2       = (const float*)d_in[7];

    // d_ws (12.5 MiB proven): Hbuf 8M | Z 4M | W2T 128K | W1bT 64K
    u16*    Hbuf = (u16*)d_ws;                               // [16384][256] bf16
    float*  Z    = (float*)((char*)d_ws + (8u << 20));       // [4096][256] f32
    u16*    W2T  = (u16*)((char*)d_ws + (12u << 20));        // 128 KiB
    u16*    W1bT = (u16*)((char*)d_ws + (12u << 20) + (128u << 10)); // 64 KiB

    // d_out scratch (dead before gemm2 writes out):
    float* candM = (float*)d_out;                            // [32][16384] f32 = 2 MiB
    float* out   = (float*)d_out;

    scanM_gemmZ_prep <<<640, 256, 0, stream>>>(pos, pos_skip, candM, x, W1, W2,
                                               Z, W1bT, W2T);
    gemm_SHsel       <<<dim3(256, 2), 256, 0, stream>>>(pos, pos_skip, candM,
                                                        x_skip, W1bT, b1, Z, Hbuf);
    gemm2_mfma       <<<dim3(128, 4), 256, 0, stream>>>(Hbuf, W2T, b2, out);
}

// Round 20
// 66.123 us; speedup vs baseline: 1.0037x; 1.0037x over previous
//
#include <hip/hip_runtime.h>
#include <hip/hip_bf16.h>

#define N_PTS 4096
#define M_PTS 16384
#define CIN   256
#define CSK   128
#define KDIM  384   // CIN + CSK
#define HDIM  256
#define NSHARD 32
#define SHPTS (N_PTS / NSHARD)   // 128

typedef unsigned int  u32;
typedef unsigned short u16;
typedef __attribute__((ext_vector_type(8))) short bf16x8;
typedef __attribute__((ext_vector_type(4))) float f32x4;

__device__ __forceinline__ u16 f2bf(float f) {
    union { float f; u32 i; } w; w.f = f;
    u32 x = w.i;
    u32 r = x + 0x7fffu + ((x >> 16) & 1u);   // RTNE
    return (u16)(r >> 16);
}

// strict "better" with lower-index tie-break (stable-sort semantics)
__device__ __forceinline__ bool ltk(float s, int p, float t, int i) {
    return (s < t) || (s == t && p < i);
}
__device__ __forceinline__ void ins3(float s, int p,
                                     float& t0, float& t1, float& t2,
                                     int& i0, int& i1, int& i2) {
    if (ltk(s, p, t2, i2)) {
        if (ltk(s, p, t1, i1)) {
            t2 = t1; i2 = i1;
            if (ltk(s, p, t0, i0)) { t1 = t0; i1 = i0; t0 = s; i0 = p; }
            else                   { t1 = s;  i1 = p; }
        } else { t2 = s; i2 = p; }
    }
}

// branchless sorted top-3 insert, strict < (ascending-index stream => stable)
#define INS3BL(s, p, t0, t1, t2, i0, i1, i2)                              \
    {                                                                     \
        float _o0 = t0, _o1 = t1, _o2 = t2;                               \
        int _a0 = i0, _a1 = i1, _a2 = i2;                                 \
        bool _c0 = (s) < _o0, _c1 = (s) < _o1, _c2 = (s) < _o2;           \
        t0 = _c0 ? (s) : _o0;              i0 = _c0 ? (p) : _a0;          \
        t1 = _c0 ? _o0 : (_c1 ? (s) : _o1); i1 = _c0 ? _a0 : (_c1 ? (p) : _a1); \
        t2 = _c1 ? _o1 : (_c2 ? (s) : _o2); i2 = _c1 ? _a1 : (_c2 ? (p) : _a2); \
    }

// branchless top-3 insert: values via min/med3, indices via cmp+sel.
// Proven bit-exact (rounds 9/14/15). Strict <, stable for ascending streams.
#define INS3MM(s, p, t0, t1, t2, i0, i1, i2)                              \
    {                                                                     \
        bool _c0 = (s) < t0, _c1 = (s) < t1, _c2 = (s) < t2;              \
        int _oi0 = i0, _oi1 = i1;                                         \
        i0 = _c0 ? (p) : i0;                                              \
        i1 = _c0 ? _oi0 : (_c1 ? (p) : i1);                               \
        i2 = _c1 ? _oi1 : (_c2 ? (p) : i2);                               \
        float _ot0 = t0, _ot1 = t1;                                       \
        t0 = fminf(t0, (s));                                              \
        t1 = __builtin_amdgcn_fmed3f(_ot0, t1, (s));                      \
        t2 = __builtin_amdgcn_fmed3f(_ot1, t2, (s));                      \
    }

// ---------------------------------------------------------------------------
// Kernel 1 (FAT)  [R18 proven, byte-identical]:
//   blocks 0..511   : min-only sharded scan (4 queries/thread, 2 blocks/CU)
//   blocks 512..639 : gemm_Z
//   blocks 640..895 : W-transpose prep: W1bT [256][128], W2T [256][256] bf16
// ---------------------------------------------------------------------------
__global__ __launch_bounds__(256) void scanM_gemmZ_prep(
    const float* __restrict__ pos,
    const float* __restrict__ pos_skip,
    float* __restrict__ candM,
    const float* __restrict__ x,
    const float* __restrict__ W1,
    const float* __restrict__ W2,
    float* __restrict__ Z,
    u16* __restrict__ W1bT,
    u16* __restrict__ W2T)
{
    const int bid = blockIdx.x;
    const int tid = threadIdx.x;

    if (bid < 512) {
        // ------------------- scanM: 4 queries per thread -------------------
        __shared__ float4 spts[SHPTS];     // 2 KB
        const int bx = bid & 15, sh = bid >> 4;
        const int pbase = sh * SHPTS;

        if (tid < SHPTS) {
            const int i = pbase + tid;
            float px = pos[3 * i], py = pos[3 * i + 1], pz = pos[3 * i + 2];
            float pn = __fadd_rn(__fadd_rn(__fmul_rn(px, px), __fmul_rn(py, py)),
                                 __fmul_rn(pz, pz));
            spts[tid] = make_float4(px, py, pz, pn);
        }

        const int mb = bx * 1024 + tid;
        float qx[4], qy[4], qz[4], qn[4];
        #pragma unroll
        for (int q = 0; q < 4; ++q) {
            const int m = mb + q * 256;
            qx[q] = pos_skip[3 * m];
            qy[q] = pos_skip[3 * m + 1];
            qz[q] = pos_skip[3 * m + 2];
            qn[q] = __fadd_rn(__fadd_rn(__fmul_rn(qx[q], qx[q]), __fmul_rn(qy[q], qy[q])),
                              __fmul_rn(qz[q], qz[q]));
        }
        __syncthreads();

        float e[4] = {3.4e38f, 3.4e38f, 3.4e38f, 3.4e38f};

        #pragma unroll 8
        for (int j = 0; j < SHPTS; ++j) {
            float4 v = spts[j];
            #pragma unroll
            for (int q = 0; q < 4; ++q) {
                float b = __fmaf_rn(qz[q], v.z, __fmaf_rn(qy[q], v.y, __fmul_rn(qx[q], v.x)));
                float s = __fadd_rn(__fmaf_rn(-2.0f, b, qn[q]), v.w);
                e[q] = fminf(e[q], s);
            }
        }

        #pragma unroll
        for (int q = 0; q < 4; ++q)
            candM[(size_t)sh * M_PTS + mb + q * 256] = e[q];
    } else if (bid < 640) {
        // ------------------- gemm_Z: Z = bf16(x) @ bf16(W1a) ---------------
        __shared__ alignas(16) u16 Bs[64][40];
        const int id = bid - 512;
        const int w = tid >> 6, l = tid & 63;
        const int bm = (id & 31) * 128;
        const int bn = (id >> 5) * 64;
        const int lr = l & 15, lg = l >> 4;

        f32x4 acc[2][4];
        #pragma unroll
        for (int mt = 0; mt < 2; ++mt)
            #pragma unroll
            for (int nt = 0; nt < 4; ++nt)
                acc[mt][nt] = (f32x4){0.f, 0.f, 0.f, 0.f};

        const int sc = tid >> 2;
        const int sk = (tid & 3) * 8;

        for (int k0 = 0; k0 < CIN; k0 += 32) {
            #pragma unroll
            for (int j = 0; j < 8; ++j)
                Bs[sc][sk + j] = f2bf(W1[(size_t)(k0 + sk + j) * HDIM + bn + sc]);
            __syncthreads();

            bf16x8 af[2];
            #pragma unroll
            for (int mt = 0; mt < 2; ++mt) {
                const float* xp = x + (size_t)(bm + w * 32 + mt * 16 + lr) * CIN + k0 + lg * 8;
                float4 h0 = *reinterpret_cast<const float4*>(xp);
                float4 h1 = *reinterpret_cast<const float4*>(xp + 4);
                af[mt][0] = (short)f2bf(h0.x); af[mt][1] = (short)f2bf(h0.y);
                af[mt][2] = (short)f2bf(h0.z); af[mt][3] = (short)f2bf(h0.w);
                af[mt][4] = (short)f2bf(h1.x); af[mt][5] = (short)f2bf(h1.y);
                af[mt][6] = (short)f2bf(h1.z); af[mt][7] = (short)f2bf(h1.w);
            }
            #pragma unroll
            for (int nt = 0; nt < 4; ++nt) {
                bf16x8 bf = *reinterpret_cast<const bf16x8*>(&Bs[nt * 16 + lr][lg * 8]);
                #pragma unroll
                for (int mt = 0; mt < 2; ++mt)
                    acc[mt][nt] = __builtin_amdgcn_mfma_f32_16x16x32_bf16(
                        af[mt], bf, acc[mt][nt], 0, 0, 0);
            }
            __syncthreads();
        }

        #pragma unroll
        for (int nt = 0; nt < 4; ++nt) {
            const int col = bn + nt * 16 + lr;
            #pragma unroll
            for (int mt = 0; mt < 2; ++mt)
                #pragma unroll
                for (int i = 0; i < 4; ++i) {
                    const int row = bm + w * 32 + mt * 16 + lg * 4 + i;
                    Z[(size_t)row * HDIM + col] = acc[mt][nt][i];
                }
        }
    } else {
        // ------------------- W-transpose prep (one output col per block) ---
        const int n = bid - 640;               // 0..255
        W2T[(size_t)n * HDIM + tid] = f2bf(W2[(size_t)tid * HDIM + n]);
        if (tid >= 128) {
            const int k = tid - 128;
            W1bT[(size_t)n * CSK + k] = f2bf(W1[(size_t)(CIN + k) * HDIM + n]);
        }
    }
}

// ---------------------------------------------------------------------------
// Kernel 2 (MFMA + fused KNN finish)  [R19 correctness-proven, byte-identical]:
// grid (256, 2) = 64 rows x 128 cols. Prologue = R16-proven select_rescan
// (results in LDS); GEMM: H = relu(bf16(x_skip)@W1bT + sum_k w_k Z[i_k] + b1).
// ---------------------------------------------------------------------------
__global__ __launch_bounds__(256) void gemm_SHsel(
    const float* __restrict__ pos,
    const float* __restrict__ pos_skip,
    const float* __restrict__ candM,
    const float* __restrict__ x_skip, const u16* __restrict__ W1bT,
    const float* __restrict__ b1, const float* __restrict__ Z,
    u16* __restrict__ H)
{
    __shared__ float sv[64][4][3];
    __shared__ int   si[64][4][3];
    __shared__ u32   ssel[64];
    __shared__ float4 nw[64];
    __shared__ uint4  ni[64];
    __shared__ alignas(16) u16 Bs[128][40];    // 10.2 KB

    const int tid  = threadIdx.x;
    const int ql   = tid >> 2;
    const int slot = tid & 3;
    const int bm   = blockIdx.x * 64;
    const int bn   = blockIdx.y * 128;
    const int m    = bm + ql;

    // ======================= Prologue: selection ============================
    {
        float t0 = 3.4e38f, t1 = 3.4e38f, t2 = 3.4e38f;
        int   s0 = 63, s1 = 63, s2 = 63;
        #pragma unroll
        for (int k = 0; k < 8; ++k) {
            const int sh = slot * 8 + k;
            float mn = candM[(size_t)sh * M_PTS + m];
            INS3BL(mn, sh, t0, t1, t2, s0, s1, s2);
        }
        sv[ql][slot][0] = t0; sv[ql][slot][1] = t1; sv[ql][slot][2] = t2;
        si[ql][slot][0] = s0; si[ql][slot][1] = s1; si[ql][slot][2] = s2;
    }
    __syncthreads();
    if (slot == 0) {
        float t0 = 3.4e38f, t1 = 3.4e38f, t2 = 3.4e38f;
        int   s0 = 63, s1 = 63, s2 = 63;
        #pragma unroll
        for (int s = 0; s < 4; ++s)
            #pragma unroll
            for (int k = 0; k < 3; ++k)
                ins3(sv[ql][s][k], si[ql][s][k], t0, t1, t2, s0, s1, s2);
        ssel[ql] = (u32)s0 | ((u32)s1 << 8) | ((u32)s2 << 16);
    }
    __syncthreads();
    const u32 sel = ssel[ql];

    if (slot < 3) {
        const int sh = (sel >> (8 * slot)) & 63;
        const int pb = sh * SHPTS;

        const float qx = pos_skip[3 * m];
        const float qy = pos_skip[3 * m + 1];
        const float qz = pos_skip[3 * m + 2];
        const float qn = __fadd_rn(__fadd_rn(__fmul_rn(qx, qx), __fmul_rn(qy, qy)),
                                   __fmul_rn(qz, qz));

        float t0 = 3.4e38f, t1 = 3.4e38f, t2 = 3.4e38f;
        int   i0 = 0x7fffffff, i1 = 0x7fffffff, i2 = 0x7fffffff;

        #pragma unroll 4
        for (int j = 0; j < SHPTS; ++j) {
            const int p = pb + j;
            float px = pos[3 * p], py = pos[3 * p + 1], pz = pos[3 * p + 2];
            float pn = __fadd_rn(__fadd_rn(__fmul_rn(px, px), __fmul_rn(py, py)),
                                 __fmul_rn(pz, pz));
            float b = __fmaf_rn(qz, pz, __fmaf_rn(qy, py, __fmul_rn(qx, px)));
            float s = __fadd_rn(__fmaf_rn(-2.0f, b, qn), pn);
            INS3MM(s, p, t0, t1, t2, i0, i1, i2);
        }
        sv[ql][slot][0] = t0; sv[ql][slot][1] = t1; sv[ql][slot][2] = t2;
        si[ql][slot][0] = i0; si[ql][slot][1] = i1; si[ql][slot][2] = i2;
    }
    __syncthreads();

    if (slot == 0) {
        float t0 = 3.4e38f, t1 = 3.4e38f, t2 = 3.4e38f;
        int   i0 = 0x7fffffff, i1 = 0x7fffffff, i2 = 0x7fffffff;
        #pragma unroll
        for (int s = 0; s < 3; ++s)
            #pragma unroll
            for (int k = 0; k < 3; ++k)
                ins3(sv[ql][s][k], si[ql][s][k], t0, t1, t2, i0, i1, i2);

        float w0 = __fdiv_rn(1.0f, fmaxf(t0, 1e-16f));
        float w1 = __fdiv_rn(1.0f, fmaxf(t1, 1e-16f));
        float w2 = __fdiv_rn(1.0f, fmaxf(t2, 1e-16f));
        float inv = __fdiv_rn(1.0f, __fadd_rn(__fadd_rn(w0, w1), w2));
        nw[ql] = make_float4(w0 * inv, w1 * inv, w2 * inv, 0.f);
        ni[ql] = make_uint4((u32)i0, (u32)i1, (u32)i2, 0u);
    }
    __syncthreads();

    // ======================= GEMM: S + interpolate ==========================
    const int w = tid >> 6, l = tid & 63;
    const int lr = l & 15, lg = l >> 4;

    f32x4 acc[8];
    #pragma unroll
    for (int nt = 0; nt < 8; ++nt) acc[nt] = (f32x4){0.f, 0.f, 0.f, 0.f};

    const int sc = tid >> 1;          // staging col 0..127
    const int sk = (tid & 1) * 16;    // k 0 or 16

    for (int k0 = 0; k0 < CSK; k0 += 32) {
        *reinterpret_cast<bf16x8*>(&Bs[sc][sk]) =
            *reinterpret_cast<const bf16x8*>(&W1bT[(size_t)(bn + sc) * CSK + k0 + sk]);
        *reinterpret_cast<bf16x8*>(&Bs[sc][sk + 8]) =
            *reinterpret_cast<const bf16x8*>(&W1bT[(size_t)(bn + sc) * CSK + k0 + sk + 8]);
        __syncthreads();

        const float* xp = x_skip + (size_t)(bm + w * 16 + lr) * CSK + k0 + lg * 8;
        float4 h0 = *reinterpret_cast<const float4*>(xp);
        float4 h1 = *reinterpret_cast<const float4*>(xp + 4);
        bf16x8 af;
        af[0] = (short)f2bf(h0.x); af[1] = (short)f2bf(h0.y);
        af[2] = (short)f2bf(h0.z); af[3] = (short)f2bf(h0.w);
        af[4] = (short)f2bf(h1.x); af[5] = (short)f2bf(h1.y);
        af[6] = (short)f2bf(h1.z); af[7] = (short)f2bf(h1.w);

        #pragma unroll
        for (int nt = 0; nt < 8; ++nt) {
            bf16x8 bf = *reinterpret_cast<const bf16x8*>(&Bs[nt * 16 + lr][lg * 8]);
            acc[nt] = __builtin_amdgcn_mfma_f32_16x16x32_bf16(af, bf, acc[nt], 0, 0, 0);
        }
        __syncthreads();
    }

    // epilogue: blend interpolated Z rows + bias + relu -> H (bf16)
    #pragma unroll
    for (int i = 0; i < 4; ++i) {
        const int lrow = w * 16 + lg * 4 + i;
        const int row  = bm + lrow;
        const float4 wv = nw[lrow];
        const uint4  iv = ni[lrow];
        const float* z0 = Z + (size_t)(iv.x & 4095u) * HDIM;  // clamp: no OOB
        const float* z1 = Z + (size_t)(iv.y & 4095u) * HDIM;
        const float* z2 = Z + (size_t)(iv.z & 4095u) * HDIM;
        #pragma unroll
        for (int nt = 0; nt < 8; ++nt) {
            const int col = bn + nt * 16 + lr;
            float zb = wv.x * z0[col] + wv.y * z1[col] + wv.z * z2[col];
            float v = acc[nt][i] + zb + b1[col];
            H[(size_t)row * HDIM + col] = f2bf(v > 0.f ? v : 0.f);
        }
    }
}

// ---------------------------------------------------------------------------
// Kernel 3 (MFMA): out = H @ W2 + b2.  H bf16, vector B-staging from W2T.
// (R18 proven, byte-identical.)
// ---------------------------------------------------------------------------
__global__ __launch_bounds__(256) void gemm2_mfma(
    const u16* __restrict__ H, const u16* __restrict__ W2T,
    const float* __restrict__ b2, float* __restrict__ out)
{
    __shared__ alignas(16) u16 Bs[64][40];
    const int tid = threadIdx.x;
    const int w = tid >> 6, l = tid & 63;
    const int bm = blockIdx.x * 128;
    const int bn = blockIdx.y * 64;
    const int lr = l & 15, lg = l >> 4;

    f32x4 acc[2][4];
    #pragma unroll
    for (int mt = 0; mt < 2; ++mt)
        #pragma unroll
        for (int nt = 0; nt < 4; ++nt)
            acc[mt][nt] = (f32x4){0.f, 0.f, 0.f, 0.f};

    const int sc = tid >> 2;
    const int sk = (tid & 3) * 8;

    for (int k0 = 0; k0 < HDIM; k0 += 32) {
        *reinterpret_cast<bf16x8*>(&Bs[sc][sk]) =
            *reinterpret_cast<const bf16x8*>(&W2T[(size_t)(bn + sc) * HDIM + k0 + sk]);
        __syncthreads();

        bf16x8 af[2];
        #pragma unroll
        for (int mt = 0; mt < 2; ++mt) {
            const int row = bm + w * 32 + mt * 16 + lr;
            af[mt] = *reinterpret_cast<const bf16x8*>(H + (size_t)row * HDIM + k0 + lg * 8);
        }
        #pragma unroll
        for (int nt = 0; nt < 4; ++nt) {
            bf16x8 bf = *reinterpret_cast<const bf16x8*>(&Bs[nt * 16 + lr][lg * 8]);
            #pragma unroll
            for (int mt = 0; mt < 2; ++mt)
                acc[mt][nt] = __builtin_amdgcn_mfma_f32_16x16x32_bf16(
                    af[mt], bf, acc[mt][nt], 0, 0, 0);
        }
        __syncthreads();
    }

    #pragma unroll
    for (int nt = 0; nt < 4; ++nt) {
        const int col = bn + nt * 16 + lr;
        const float bias = b2[col];
        #pragma unroll
        for (int mt = 0; mt < 2; ++mt)
            #pragma unroll
            for (int i = 0; i < 4; ++i) {
                const int row = bm + w * 32 + mt * 16 + lg * 4 + i;
                out[(size_t)row * HDIM + col] = acc[mt][nt][i] + bias;
            }
    }
}

// ---------------------------------------------------------------------------
extern "C" void kernel_launch(void* const* d_in, const int* in_sizes, int n_in,
                              void* d_out, int out_size, void* d_ws, size_t ws_size,
                              hipStream_t stream) {
    const float* x        = (const float*)d_in[0];
    const float* pos      = (const float*)d_in[1];
    const float* x_skip   = (const float*)d_in[2];
    const float* pos_skip = (const float*)d_in[3];
    const float* W1       = (const float*)d_in[4];
    const float* b1       = (const float*)d_in[5];
    const float* W2       = (const float*)d_in[6];
    const float* b2       = (const float*)d_in[7];

    // d_ws (12.5 MiB proven): Hbuf 8M | Z 4M | W2T 128K | W1bT 64K
    u16*    Hbuf = (u16*)d_ws;                               // [16384][256] bf16
    float*  Z    = (float*)((char*)d_ws + (8u << 20));       // [4096][256] f32
    u16*    W2T  = (u16*)((char*)d_ws + (12u << 20));        // 128 KiB
    u16*    W1bT = (u16*)((char*)d_ws + (12u << 20) + (128u << 10)); // 64 KiB

    // d_out scratch (dead before gemm2 writes out):
    float* candM = (float*)d_out;                            // [32][16384] f32 = 2 MiB
    float* out   = (float*)d_out;

    scanM_gemmZ_prep <<<896, 256, 0, stream>>>(pos, pos_skip, candM, x, W1, W2,
                                               Z, W1bT, W2T);
    gemm_SHsel       <<<dim3(256, 2), 256, 0, stream>>>(pos, pos_skip, candM,
                                                        x_skip, W1bT, b1, Z, Hbuf);
    gemm2_mfma       <<<dim3(128, 4), 256, 0, stream>>>(Hbuf, W2T, b2, out);
}

// Round 21
// 60.490 us; speedup vs baseline: 1.0971x; 1.0931x over previous
//
#include <hip/hip_runtime.h>
#include <hip/hip_bf16.h>

#define N_PTS 4096
#define M_PTS 16384
#define CIN   256
#define CSK   128
#define KDIM  384   // CIN + CSK
#define HDIM  256
#define NSHARD 32
#define SHPTS (N_PTS / NSHARD)   // 128

typedef unsigned int  u32;
typedef unsigned short u16;
typedef __attribute__((ext_vector_type(8))) short bf16x8;
typedef __attribute__((ext_vector_type(4))) float f32x4;

__device__ __forceinline__ u16 f2bf(float f) {
    union { float f; u32 i; } w; w.f = f;
    u32 x = w.i;
    u32 r = x + 0x7fffu + ((x >> 16) & 1u);   // RTNE
    return (u16)(r >> 16);
}

// strict "better" with lower-index tie-break (stable-sort semantics)
__device__ __forceinline__ bool ltk(float s, int p, float t, int i) {
    return (s < t) || (s == t && p < i);
}
__device__ __forceinline__ void ins3(float s, int p,
                                     float& t0, float& t1, float& t2,
                                     int& i0, int& i1, int& i2) {
    if (ltk(s, p, t2, i2)) {
        if (ltk(s, p, t1, i1)) {
            t2 = t1; i2 = i1;
            if (ltk(s, p, t0, i0)) { t1 = t0; i1 = i0; t0 = s; i0 = p; }
            else                   { t1 = s;  i1 = p; }
        } else { t2 = s; i2 = p; }
    }
}

// branchless sorted top-3 insert, strict < (ascending-index stream => stable)
#define INS3BL(s, p, t0, t1, t2, i0, i1, i2)                              \
    {                                                                     \
        float _o0 = t0, _o1 = t1, _o2 = t2;                               \
        int _a0 = i0, _a1 = i1, _a2 = i2;                                 \
        bool _c0 = (s) < _o0, _c1 = (s) < _o1, _c2 = (s) < _o2;           \
        t0 = _c0 ? (s) : _o0;              i0 = _c0 ? (p) : _a0;          \
        t1 = _c0 ? _o0 : (_c1 ? (s) : _o1); i1 = _c0 ? _a0 : (_c1 ? (p) : _a1); \
        t2 = _c1 ? _o1 : (_c2 ? (s) : _o2); i2 = _c1 ? _a1 : (_c2 ? (p) : _a2); \
    }

// branchless top-3 insert: values via min/med3, indices via cmp+sel.
// Proven bit-exact (rounds 9/14/15). Strict <, stable for ascending streams.
#define INS3MM(s, p, t0, t1, t2, i0, i1, i2)                              \
    {                                                                     \
        bool _c0 = (s) < t0, _c1 = (s) < t1, _c2 = (s) < t2;              \
        int _oi0 = i0, _oi1 = i1;                                         \
        i0 = _c0 ? (p) : i0;                                              \
        i1 = _c0 ? _oi0 : (_c1 ? (p) : i1);                               \
        i2 = _c1 ? _oi1 : (_c2 ? (p) : i2);                               \
        float _ot0 = t0, _ot1 = t1;                                       \
        t0 = fminf(t0, (s));                                              \
        t1 = __builtin_amdgcn_fmed3f(_ot0, t1, (s));                      \
        t2 = __builtin_amdgcn_fmed3f(_ot1, t2, (s));                      \
    }

// ---------------------------------------------------------------------------
// Kernel 1 (FAT)  [R18 proven]:
//   blocks 0..511   : min-only sharded scan (4 queries/thread, 2 blocks/CU)
//   blocks 512..639 : gemm_Z
//   blocks 640..895 : W-transpose prep: W1bT [256][128], W2T [256][256] bf16
// ---------------------------------------------------------------------------
__global__ __launch_bounds__(256) void scanM_gemmZ_prep(
    const float* __restrict__ pos,
    const float* __restrict__ pos_skip,
    float* __restrict__ candM,
    const float* __restrict__ x,
    const float* __restrict__ W1,
    const float* __restrict__ W2,
    float* __restrict__ Z,
    u16* __restrict__ W1bT,
    u16* __restrict__ W2T)
{
    const int bid = blockIdx.x;
    const int tid = threadIdx.x;

    if (bid < 512) {
        // ------------------- scanM: 4 queries per thread -------------------
        __shared__ float4 spts[SHPTS];     // 2 KB
        const int bx = bid & 15, sh = bid >> 4;
        const int pbase = sh * SHPTS;

        if (tid < SHPTS) {
            const int i = pbase + tid;
            float px = pos[3 * i], py = pos[3 * i + 1], pz = pos[3 * i + 2];
            float pn = __fadd_rn(__fadd_rn(__fmul_rn(px, px), __fmul_rn(py, py)),
                                 __fmul_rn(pz, pz));
            spts[tid] = make_float4(px, py, pz, pn);
        }

        const int mb = bx * 1024 + tid;
        float qx[4], qy[4], qz[4], qn[4];
        #pragma unroll
        for (int q = 0; q < 4; ++q) {
            const int m = mb + q * 256;
            qx[q] = pos_skip[3 * m];
            qy[q] = pos_skip[3 * m + 1];
            qz[q] = pos_skip[3 * m + 2];
            qn[q] = __fadd_rn(__fadd_rn(__fmul_rn(qx[q], qx[q]), __fmul_rn(qy[q], qy[q])),
                              __fmul_rn(qz[q], qz[q]));
        }
        __syncthreads();

        float e[4] = {3.4e38f, 3.4e38f, 3.4e38f, 3.4e38f};

        #pragma unroll 8
        for (int j = 0; j < SHPTS; ++j) {
            float4 v = spts[j];
            #pragma unroll
            for (int q = 0; q < 4; ++q) {
                float b = __fmaf_rn(qz[q], v.z, __fmaf_rn(qy[q], v.y, __fmul_rn(qx[q], v.x)));
                float s = __fadd_rn(__fmaf_rn(-2.0f, b, qn[q]), v.w);
                e[q] = fminf(e[q], s);
            }
        }

        #pragma unroll
        for (int q = 0; q < 4; ++q)
            candM[(size_t)sh * M_PTS + mb + q * 256] = e[q];
    } else if (bid < 640) {
        // ------------------- gemm_Z: Z = bf16(x) @ bf16(W1a) ---------------
        __shared__ alignas(16) u16 Bs[64][40];
        const int id = bid - 512;
        const int w = tid >> 6, l = tid & 63;
        const int bm = (id & 31) * 128;
        const int bn = (id >> 5) * 64;
        const int lr = l & 15, lg = l >> 4;

        f32x4 acc[2][4];
        #pragma unroll
        for (int mt = 0; mt < 2; ++mt)
            #pragma unroll
            for (int nt = 0; nt < 4; ++nt)
                acc[mt][nt] = (f32x4){0.f, 0.f, 0.f, 0.f};

        const int sc = tid >> 2;
        const int sk = (tid & 3) * 8;

        for (int k0 = 0; k0 < CIN; k0 += 32) {
            #pragma unroll
            for (int j = 0; j < 8; ++j)
                Bs[sc][sk + j] = f2bf(W1[(size_t)(k0 + sk + j) * HDIM + bn + sc]);
            __syncthreads();

            bf16x8 af[2];
            #pragma unroll
            for (int mt = 0; mt < 2; ++mt) {
                const float* xp = x + (size_t)(bm + w * 32 + mt * 16 + lr) * CIN + k0 + lg * 8;
                float4 h0 = *reinterpret_cast<const float4*>(xp);
                float4 h1 = *reinterpret_cast<const float4*>(xp + 4);
                af[mt][0] = (short)f2bf(h0.x); af[mt][1] = (short)f2bf(h0.y);
                af[mt][2] = (short)f2bf(h0.z); af[mt][3] = (short)f2bf(h0.w);
                af[mt][4] = (short)f2bf(h1.x); af[mt][5] = (short)f2bf(h1.y);
                af[mt][6] = (short)f2bf(h1.z); af[mt][7] = (short)f2bf(h1.w);
            }
            #pragma unroll
            for (int nt = 0; nt < 4; ++nt) {
                bf16x8 bf = *reinterpret_cast<const bf16x8*>(&Bs[nt * 16 + lr][lg * 8]);
                #pragma unroll
                for (int mt = 0; mt < 2; ++mt)
                    acc[mt][nt] = __builtin_amdgcn_mfma_f32_16x16x32_bf16(
                        af[mt], bf, acc[mt][nt], 0, 0, 0);
            }
            __syncthreads();
        }

        #pragma unroll
        for (int nt = 0; nt < 4; ++nt) {
            const int col = bn + nt * 16 + lr;
            #pragma unroll
            for (int mt = 0; mt < 2; ++mt)
                #pragma unroll
                for (int i = 0; i < 4; ++i) {
                    const int row = bm + w * 32 + mt * 16 + lg * 4 + i;
                    Z[(size_t)row * HDIM + col] = acc[mt][nt][i];
                }
        }
    } else {
        // ------------------- W-transpose prep (one output col per block) ---
        const int n = bid - 640;               // 0..255
        W2T[(size_t)n * HDIM + tid] = f2bf(W2[(size_t)tid * HDIM + n]);
        if (tid >= 128) {
            const int k = tid - 128;
            W1bT[(size_t)n * CSK + k] = f2bf(W1[(size_t)(CIN + k) * HDIM + n]);
        }
    }
}

// ---------------------------------------------------------------------------
// Kernel 2: shard selection + rescan + merge + weights. (R16 proven.)
// ---------------------------------------------------------------------------
__global__ __launch_bounds__(256) void knn_select_rescan(
    const float* __restrict__ pos,
    const float* __restrict__ pos_skip,
    const float* __restrict__ candM,
    float4* __restrict__ nbrw, uint4* __restrict__ nbri)
{
    __shared__ float sv[64][4][3];
    __shared__ int   si[64][4][3];
    __shared__ u32   ssel[64];
    const int tid  = threadIdx.x;
    const int ql   = tid >> 2;
    const int slot = tid & 3;
    const int m = blockIdx.x * 64 + ql;

    {
        float t0 = 3.4e38f, t1 = 3.4e38f, t2 = 3.4e38f;
        int   s0 = 63, s1 = 63, s2 = 63;
        #pragma unroll
        for (int k = 0; k < 8; ++k) {
            const int sh = slot * 8 + k;
            float mn = candM[(size_t)sh * M_PTS + m];
            INS3BL(mn, sh, t0, t1, t2, s0, s1, s2);
        }
        sv[ql][slot][0] = t0; sv[ql][slot][1] = t1; sv[ql][slot][2] = t2;
        si[ql][slot][0] = s0; si[ql][slot][1] = s1; si[ql][slot][2] = s2;
    }
    __syncthreads();
    if (slot == 0) {
        float t0 = 3.4e38f, t1 = 3.4e38f, t2 = 3.4e38f;
        int   s0 = 63, s1 = 63, s2 = 63;
        #pragma unroll
        for (int s = 0; s < 4; ++s)
            #pragma unroll
            for (int k = 0; k < 3; ++k)
                ins3(sv[ql][s][k], si[ql][s][k], t0, t1, t2, s0, s1, s2);
        ssel[ql] = (u32)s0 | ((u32)s1 << 8) | ((u32)s2 << 16);
    }
    __syncthreads();
    const u32 sel = ssel[ql];

    if (slot < 3) {
        const int sh = (sel >> (8 * slot)) & 63;
        const int pb = sh * SHPTS;

        const float qx = pos_skip[3 * m];
        const float qy = pos_skip[3 * m + 1];
        const float qz = pos_skip[3 * m + 2];
        const float qn = __fadd_rn(__fadd_rn(__fmul_rn(qx, qx), __fmul_rn(qy, qy)),
                                   __fmul_rn(qz, qz));

        float t0 = 3.4e38f, t1 = 3.4e38f, t2 = 3.4e38f;
        int   i0 = 0x7fffffff, i1 = 0x7fffffff, i2 = 0x7fffffff;

        #pragma unroll 4
        for (int j = 0; j < SHPTS; ++j) {
            const int p = pb + j;
            float px = pos[3 * p], py = pos[3 * p + 1], pz = pos[3 * p + 2];
            float pn = __fadd_rn(__fadd_rn(__fmul_rn(px, px), __fmul_rn(py, py)),
                                 __fmul_rn(pz, pz));
            float b = __fmaf_rn(qz, pz, __fmaf_rn(qy, py, __fmul_rn(qx, px)));
            float s = __fadd_rn(__fmaf_rn(-2.0f, b, qn), pn);
            INS3MM(s, p, t0, t1, t2, i0, i1, i2);
        }
        sv[ql][slot][0] = t0; sv[ql][slot][1] = t1; sv[ql][slot][2] = t2;
        si[ql][slot][0] = i0; si[ql][slot][1] = i1; si[ql][slot][2] = i2;
    }
    __syncthreads();

    if (slot == 0) {
        float t0 = 3.4e38f, t1 = 3.4e38f, t2 = 3.4e38f;
        int   i0 = 0x7fffffff, i1 = 0x7fffffff, i2 = 0x7fffffff;
        #pragma unroll
        for (int s = 0; s < 3; ++s)
            #pragma unroll
            for (int k = 0; k < 3; ++k)
                ins3(sv[ql][s][k], si[ql][s][k], t0, t1, t2, i0, i1, i2);

        float w0 = __fdiv_rn(1.0f, fmaxf(t0, 1e-16f));
        float w1 = __fdiv_rn(1.0f, fmaxf(t1, 1e-16f));
        float w2 = __fdiv_rn(1.0f, fmaxf(t2, 1e-16f));
        float inv = __fdiv_rn(1.0f, __fadd_rn(__fadd_rn(w0, w1), w2));
        nbrw[m] = make_float4(w0 * inv, w1 * inv, w2 * inv, 0.f);
        nbri[m] = make_uint4((u32)i0, (u32)i1, (u32)i2, 0u);
    }
}

// ---------------------------------------------------------------------------
// Kernel 3 (MFMA): S = bf16(x_skip) @ W1bT; epilogue fuses interpolation:
// H = relu(S + sum_k w_k Z[i_k] + b1), H stored bf16. (R18 proven.)
// ---------------------------------------------------------------------------
__global__ __launch_bounds__(256) void gemm_SH(
    const float* __restrict__ x_skip, const u16* __restrict__ W1bT,
    const float* __restrict__ b1, const float* __restrict__ Z,
    const float4* __restrict__ nbrw, const uint4* __restrict__ nbri,
    u16* __restrict__ H)
{
    __shared__ alignas(16) u16 Bs[64][40];
    const int tid = threadIdx.x;
    const int w = tid >> 6, l = tid & 63;
    const int bm = blockIdx.x * 128;
    const int bn = blockIdx.y * 64;
    const int lr = l & 15, lg = l >> 4;

    f32x4 acc[2][4];
    #pragma unroll
    for (int mt = 0; mt < 2; ++mt)
        #pragma unroll
        for (int nt = 0; nt < 4; ++nt)
            acc[mt][nt] = (f32x4){0.f, 0.f, 0.f, 0.f};

    const int sc = tid >> 2;
    const int sk = (tid & 3) * 8;

    for (int k0 = 0; k0 < CSK; k0 += 32) {
        *reinterpret_cast<bf16x8*>(&Bs[sc][sk]) =
            *reinterpret_cast<const bf16x8*>(&W1bT[(size_t)(bn + sc) * CSK + k0 + sk]);
        __syncthreads();

        bf16x8 af[2];
        #pragma unroll
        for (int mt = 0; mt < 2; ++mt) {
            const float* xp = x_skip + (size_t)(bm + w * 32 + mt * 16 + lr) * CSK + k0 + lg * 8;
            float4 h0 = *reinterpret_cast<const float4*>(xp);
            float4 h1 = *reinterpret_cast<const float4*>(xp + 4);
            af[mt][0] = (short)f2bf(h0.x); af[mt][1] = (short)f2bf(h0.y);
            af[mt][2] = (short)f2bf(h0.z); af[mt][3] = (short)f2bf(h0.w);
            af[mt][4] = (short)f2bf(h1.x); af[mt][5] = (short)f2bf(h1.y);
            af[mt][6] = (short)f2bf(h1.z); af[mt][7] = (short)f2bf(h1.w);
        }
        #pragma unroll
        for (int nt = 0; nt < 4; ++nt) {
            bf16x8 bf = *reinterpret_cast<const bf16x8*>(&Bs[nt * 16 + lr][lg * 8]);
            #pragma unroll
            for (int mt = 0; mt < 2; ++mt)
                acc[mt][nt] = __builtin_amdgcn_mfma_f32_16x16x32_bf16(
                    af[mt], bf, acc[mt][nt], 0, 0, 0);
        }
        __syncthreads();
    }

    // epilogue: blend interpolated Z rows + bias + relu -> H (bf16)
    #pragma unroll
    for (int mt = 0; mt < 2; ++mt) {
        #pragma unroll
        for (int i = 0; i < 4; ++i) {
            const int row = bm + w * 32 + mt * 16 + lg * 4 + i;
            const float4 wv = nbrw[row];
            const uint4  iv = nbri[row];
            const float* z0 = Z + (size_t)(iv.x & 4095u) * HDIM;  // clamp: no OOB
            const float* z1 = Z + (size_t)(iv.y & 4095u) * HDIM;
            const float* z2 = Z + (size_t)(iv.z & 4095u) * HDIM;
            #pragma unroll
            for (int nt = 0; nt < 4; ++nt) {
                const int col = bn + nt * 16 + lr;
                float zb = wv.x * z0[col] + wv.y * z1[col] + wv.z * z2[col];
                float v = acc[mt][nt][i] + zb + b1[col];
                H[(size_t)row * HDIM + col] = f2bf(v > 0.f ? v : 0.f);
            }
        }
    }
}

// ---------------------------------------------------------------------------
// Kernel 4 (MFMA): out = H @ W2 + b2.  H bf16, vector B-staging from W2T.
// (R18 proven.)
// ---------------------------------------------------------------------------
__global__ __launch_bounds__(256) void gemm2_mfma(
    const u16* __restrict__ H, const u16* __restrict__ W2T,
    const float* __restrict__ b2, float* __restrict__ out)
{
    __shared__ alignas(16) u16 Bs[64][40];
    const int tid = threadIdx.x;
    const int w = tid >> 6, l = tid & 63;
    const int bm = blockIdx.x * 128;
    const int bn = blockIdx.y * 64;
    const int lr = l & 15, lg = l >> 4;

    f32x4 acc[2][4];
    #pragma unroll
    for (int mt = 0; mt < 2; ++mt)
        #pragma unroll
        for (int nt = 0; nt < 4; ++nt)
            acc[mt][nt] = (f32x4){0.f, 0.f, 0.f, 0.f};

    const int sc = tid >> 2;
    const int sk = (tid & 3) * 8;

    for (int k0 = 0; k0 < HDIM; k0 += 32) {
        *reinterpret_cast<bf16x8*>(&Bs[sc][sk]) =
            *reinterpret_cast<const bf16x8*>(&W2T[(size_t)(bn + sc) * HDIM + k0 + sk]);
        __syncthreads();

        bf16x8 af[2];
        #pragma unroll
        for (int mt = 0; mt < 2; ++mt) {
            const int row = bm + w * 32 + mt * 16 + lr;
            af[mt] = *reinterpret_cast<const bf16x8*>(H + (size_t)row * HDIM + k0 + lg * 8);
        }
        #pragma unroll
        for (int nt = 0; nt < 4; ++nt) {
            bf16x8 bf = *reinterpret_cast<const bf16x8*>(&Bs[nt * 16 + lr][lg * 8]);
            #pragma unroll
            for (int mt = 0; mt < 2; ++mt)
                acc[mt][nt] = __builtin_amdgcn_mfma_f32_16x16x32_bf16(
                    af[mt], bf, acc[mt][nt], 0, 0, 0);
        }
        __syncthreads();
    }

    #pragma unroll
    for (int nt = 0; nt < 4; ++nt) {
        const int col = bn + nt * 16 + lr;
        const float bias = b2[col];
        #pragma unroll
        for (int mt = 0; mt < 2; ++mt)
            #pragma unroll
            for (int i = 0; i < 4; ++i) {
                const int row = bm + w * 32 + mt * 16 + lg * 4 + i;
                out[(size_t)row * HDIM + col] = acc[mt][nt][i] + bias;
            }
    }
}

// ---------------------------------------------------------------------------
extern "C" void kernel_launch(void* const* d_in, const int* in_sizes, int n_in,
                              void* d_out, int out_size, void* d_ws, size_t ws_size,
                              hipStream_t stream) {
    const float* x        = (const float*)d_in[0];
    const float* pos      = (const float*)d_in[1];
    const float* x_skip   = (const float*)d_in[2];
    const float* pos_skip = (const float*)d_in[3];
    const float* W1       = (const float*)d_in[4];
    const float* b1       = (const float*)d_in[5];
    const float* W2       = (const float*)d_in[6];
    const float* b2       = (const float*)d_in[7];

    // d_ws (12.5 MiB proven): Hbuf 8M | Z 4M | nbrw 256K | nbri 256K |
    //                         W2T 128K | W1bT 64K
    u16*    Hbuf = (u16*)d_ws;                               // [16384][256] bf16
    float*  Z    = (float*)((char*)d_ws + (8u << 20));       // [4096][256] f32
    float4* nbrw = (float4*)((char*)d_ws + (12u << 20));
    uint4*  nbri = (uint4*)((char*)d_ws + (12u << 20) + (256u << 10));
    u16*    W2T  = (u16*)((char*)d_ws + (12u << 20) + (512u << 10));   // 128 KiB
    u16*    W1bT = (u16*)((char*)d_ws + (12u << 20) + (640u << 10));   // 64 KiB

    // d_out scratch (dead before gemm2 writes out):
    float* candM = (float*)d_out;                            // [32][16384] f32 = 2 MiB
    float* out   = (float*)d_out;

    scanM_gemmZ_prep <<<896, 256, 0, stream>>>(pos, pos_skip, candM, x, W1, W2,
                                               Z, W1bT, W2T);
    knn_select_rescan<<<256, 256, 0, stream>>>(pos, pos_skip, candM, nbrw, nbri);
    gemm_SH          <<<dim3(128, 4), 256, 0, stream>>>(x_skip, W1bT, b1, Z, nbrw, nbri, Hbuf);
    gemm2_mfma       <<<dim3(128, 4), 256, 0, stream>>>(Hbuf, W2T, b2, out);
}